// Round 9
// baseline (290.132 us; speedup 1.0000x reference)
//
#include <hip/hip_runtime.h>

// Round 9: round-8 quad-split with the right-chain orientation bug fixed.
//
// Round-8 failure: a unified STEP macro applied the left-chain contraction
// acc[k] = sum_dd v[dd]*wf[dd*4+k]  (v^T M)  to BOTH sides; the right chain
// needs M r. With wf[dd*4+k] = W[row h*4+dd][f][base_e+k] (one row's 4 e's
// per float4), the right chain must accumulate over float4 COMPONENTS:
// acc[dd] = sum_k r[base_e+k]*wf[dd*4+k]. Separate STEP_L / STEP_R restore
// the round-6/7-verified algebra. Same instruction counts; perf design
// unchanged from round 8:
//  - 4 lanes/batch: lane j owns (f=j&1, bond-half h=j>>1); 8 dwordx4
//    weights/site/lane, double-buffered (64 VGPR) -> fits <=128 budget.
//  - exchange via quad_perm DPP (xor1 add = f-sum, commutative -> bitwise
//    identical across the pair; xor2 mov = half allgather). Zero DS.
//  - x via LDS double-buffered 16-site chunks; weights global->regs (L1).
//  - block 256 = 32 batches x {left,right}; grid 512 -> 8 waves/CU, 2/SIMD.

#define NSITES 784
#define ODIM   10
#define LABEL  392

__device__ __forceinline__ float dpp_xor1(float x) {   // quad_perm [1,0,3,2]
    return __int_as_float(__builtin_amdgcn_update_dpp(0, __float_as_int(x), 0xB1, 0xF, 0xF, true));
}
__device__ __forceinline__ float dpp_xor2(float x) {   // quad_perm [2,3,0,1]
    return __int_as_float(__builtin_amdgcn_update_dpp(0, __float_as_int(x), 0x4E, 0xF, 0xF, true));
}

__global__ __launch_bounds__(256, 2) void mps_fused(
    const float* __restrict__ x,      // [B, N]
    const float* __restrict__ w0,     // [2, 8]
    const float* __restrict__ Wl,     // [391][d][f][e]
    const float* __restrict__ wlab,   // [8][2][8][10]
    const float* __restrict__ Wr,     // [390][d][f][e]
    const float* __restrict__ wlast,  // [8][2]
    float* __restrict__ out)          // [B, 10]
{
    __shared__ float xbl[2][16][32];  // [buf][site-slot][batch]
    __shared__ float xbr[2][16][32];
    __shared__ float wlsh[1280];
    __shared__ float vls[32][8];
    __shared__ float rvs[32][8];

    const int tid  = threadIdx.x;
    const int wave = tid >> 6;
    const int lane = tid & 63;
    const int side = wave >> 1;                       // 0 = left, 1 = right
    const int j    = lane & 3;                        // lane within quad
    const int f    = j & 1;                           // phi component owned
    const int h    = j >> 1;                          // bond-half owned
    const int g    = (wave & 1) * 16 + (lane >> 2);   // batch in block 0..31
    const int b0   = blockIdx.x * 32;

    // ---- cooperative x staging ----
    const int sx = tid >> 7;          // 0 left, 1 right
    const int sk = (tid >> 5) & 3;    // float4 site-slot group
    const int sg = tid & 31;          // batch
    float4 xreg;
    auto stageA = [&](int w) {        // global -> regs
        const int c = sx ? (48 - w) : w;
        xreg = *(const float4*)(x + (size_t)(b0 + sg) * NSITES + 16 * c + 4 * sk);
    };
    auto stageB = [&](int buf) {      // regs -> LDS
        float (*xb)[32] = sx ? xbr[buf] : xbl[buf];
        xb[4 * sk + 0][sg] = xreg.x;
        xb[4 * sk + 1][sg] = xreg.y;
        xb[4 * sk + 2][sg] = xreg.z;
        xb[4 * sk + 3][sg] = xreg.w;
    };

    // ---- per-lane weight stream ----
    // Both sides: dst[dd]   = W[h*4+dd][f][own-e-half..+3]
    //             dst[4+dd] = (left)  W[(1-h)*4+dd][f][own-e-half..+3]
    //                         (right) W[h*4+dd][f][other-e-half..+3]
    const int off0 = h * 64 + f * 8 + h * 4;
    const int off1 = side ? (h * 64 + f * 8 + (1 - h) * 4)
                          : ((1 - h) * 64 + f * 8 + h * 4);
    const int   WSTEP = side ? -128 : 128;
    const float* wpre = side ? (Wr + 389 * 128) : Wl;

    float4 wA[8], wB[8];
    auto loadW = [&](float4* dst) {
        #pragma unroll
        for (int dd = 0; dd < 4; ++dd) {
            dst[dd]     = *(const float4*)(wpre + off0 + dd * 16);
            dst[4 + dd] = *(const float4*)(wpre + off1 + dd * 16);
        }
        wpre += WSTEP;
    };
    loadW(wA);            // site k=0
    loadW(wB);            // site k=1 (in flight)

    // ---- boundary init: vA = own-half, vB = other-half ----
    float vA[4], vB[4];
    if (side == 0) {
        const float p = x[(size_t)(b0 + g) * NSITES];
        const float q = 1.0f - p;
        #pragma unroll
        for (int dd = 0; dd < 4; ++dd) {
            vA[dd] = fmaf(q, w0[h * 4 + dd],       p * w0[8 + h * 4 + dd]);
            vB[dd] = fmaf(q, w0[(1 - h) * 4 + dd], p * w0[8 + (1 - h) * 4 + dd]);
        }
    } else {
        const float p = x[(size_t)(b0 + g) * NSITES + NSITES - 1];
        const float q = 1.0f - p;
        #pragma unroll
        for (int dd = 0; dd < 4; ++dd) {
            vA[dd] = fmaf(q, wlast[2 * (h * 4 + dd)],       p * wlast[2 * (h * 4 + dd) + 1]);
            vB[dd] = fmaf(q, wlast[2 * ((1 - h) * 4 + dd)], p * wlast[2 * ((1 - h) * 4 + dd) + 1]);
        }
    }

// LEFT step: v_new[e=h*4+k] = sum_f phi_f sum_d v[d] W[d][f][e]
//   vA[dd]=v[h*4+dd] pairs wf rows h*4+dd; vB pairs rows (1-h)*4+dd.
#define STEP_L(W, XS, SLOT, PF)                                         \
    {                                                                   \
        const float p  = (XS)[(SLOT)][g];                               \
        const float sf = f ? p : 1.0f - p;                              \
        const float* wf = (const float*)(W);                            \
        float acc[4];                                                   \
        _Pragma("unroll") for (int k = 0; k < 4; ++k)                   \
            acc[k] = vA[0] * wf[k];                                     \
        _Pragma("unroll") for (int dd = 1; dd < 4; ++dd)                \
            _Pragma("unroll") for (int k = 0; k < 4; ++k)               \
                acc[k] = fmaf(vA[dd], wf[dd * 4 + k], acc[k]);          \
        _Pragma("unroll") for (int dd = 0; dd < 4; ++dd)                \
            _Pragma("unroll") for (int k = 0; k < 4; ++k)               \
                acc[k] = fmaf(vB[dd], wf[16 + dd * 4 + k], acc[k]);     \
        _Pragma("unroll") for (int k = 0; k < 4; ++k) {                 \
            const float t = sf * acc[k];                                \
            const float u = t + dpp_xor1(t);     /* sum over f */       \
            vA[k] = u;                                                  \
            vB[k] = dpp_xor2(u);                 /* other half */       \
        }                                                               \
        if (PF) loadW(W);                                               \
    }
// RIGHT step: r_new[d=h*4+dd] = sum_f phi_f sum_e W[d][f][e] r[e]
//   dot over float4 COMPONENTS: wf[dd*4+k] = W[h*4+dd][f][h*4+k] pairs
//   vA[k]=r[h*4+k]; wf[16+dd*4+k] = W[h*4+dd][f][(1-h)*4+k] pairs vB[k].
#define STEP_R(W, XS, SLOT, PF)                                         \
    {                                                                   \
        const float p  = (XS)[(SLOT)][g];                               \
        const float sf = f ? p : 1.0f - p;                              \
        const float* wf = (const float*)(W);                            \
        float acc[4];                                                   \
        _Pragma("unroll") for (int dd = 0; dd < 4; ++dd)                \
            acc[dd] = vA[0] * wf[dd * 4];                               \
        _Pragma("unroll") for (int k = 1; k < 4; ++k)                   \
            _Pragma("unroll") for (int dd = 0; dd < 4; ++dd)            \
                acc[dd] = fmaf(vA[k], wf[dd * 4 + k], acc[dd]);         \
        _Pragma("unroll") for (int k = 0; k < 4; ++k)                   \
            _Pragma("unroll") for (int dd = 0; dd < 4; ++dd)            \
                acc[dd] = fmaf(vB[k], wf[16 + dd * 4 + k], acc[dd]);    \
        _Pragma("unroll") for (int dd = 0; dd < 4; ++dd) {              \
            const float t = sf * acc[dd];                               \
            const float u = t + dpp_xor1(t);                            \
            vA[dd] = u;                                                 \
            vB[dd] = dpp_xor2(u);                                       \
        }                                                               \
        if (PF) loadW(W);                                               \
    }

    // ---- prologue: stage window 0 + wlab ----
    stageA(0); stageB(0);
    for (int k2 = tid; k2 < 320; k2 += 256)
        *(float4*)&wlsh[k2 * 4] = *(const float4*)&wlab[k2 * 4];
    __syncthreads();

    // ---- window 0: 15 sites (left slots 1..15, right slots 14..0) ----
    stageA(1);
    if (side == 0) {
        STEP_L(wA, xbl[0], 1, 1)
        #pragma unroll 2
        for (int t2 = 0; t2 < 7; ++t2) {
            STEP_L(wB, xbl[0], 2 * t2 + 2, 1)
            STEP_L(wA, xbl[0], 2 * t2 + 3, 1)
        }
    } else {
        STEP_R(wA, xbr[0], 14, 1)
        #pragma unroll 2
        for (int t2 = 0; t2 < 7; ++t2) {
            STEP_R(wB, xbr[0], 13 - 2 * t2, 1)
            STEP_R(wA, xbr[0], 12 - 2 * t2, 1)
        }
    }
    stageB(1);
    __syncthreads();

    // ---- windows 1..23: 16 sites each ----
    #pragma unroll 1
    for (int w = 1; w <= 23; ++w) {
        stageA(w + 1);
        const int buf = w & 1;
        if (side == 0) {
            #pragma unroll 2
            for (int t2 = 0; t2 < 8; ++t2) {
                STEP_L(wB, xbl[buf], 2 * t2, 1)
                STEP_L(wA, xbl[buf], 2 * t2 + 1, 1)
            }
        } else {
            #pragma unroll 2
            for (int t2 = 0; t2 < 8; ++t2) {
                STEP_R(wB, xbr[buf], 15 - 2 * t2, 1)
                STEP_R(wA, xbr[buf], 14 - 2 * t2, 1)
            }
        }
        stageB(buf ^ 1);
        __syncthreads();
    }

    // ---- window 24 (buf 0): left 8 sites (slots 0..7), right 7 (15..9) ----
    if (side == 0) {
        STEP_L(wB, xbl[0], 0, 1) STEP_L(wA, xbl[0], 1, 1)
        STEP_L(wB, xbl[0], 2, 1) STEP_L(wA, xbl[0], 3, 1)
        STEP_L(wB, xbl[0], 4, 1) STEP_L(wA, xbl[0], 5, 1)
        STEP_L(wB, xbl[0], 6, 0) STEP_L(wA, xbl[0], 7, 0)
    } else {
        STEP_R(wB, xbr[0], 15, 1) STEP_R(wA, xbr[0], 14, 1)
        STEP_R(wB, xbr[0], 13, 1) STEP_R(wA, xbr[0], 12, 1)
        STEP_R(wB, xbr[0], 11, 1)
        STEP_R(wA, xbr[0], 10, 0) STEP_R(wB, xbr[0], 9, 0)
    }

    // ---- deposit boundary vectors (j==0: f=0,h=0 -> vA=v[0..3],vB=v[4..7])
    if (j == 0) {
        float* dst = (side == 0) ? &vls[g][0] : &rvs[g][0];
        dst[0] = vA[0]; dst[1] = vA[1]; dst[2] = vA[2]; dst[3] = vA[3];
        dst[4] = vB[0]; dst[5] = vB[1]; dst[6] = vB[2]; dst[7] = vB[3];
    }
    __syncthreads();

    // ---- fused label-site combine: 32 batches x 10 outputs ----
    #pragma unroll
    for (int rr = 0; rr < 2; ++rr) {
        const int idx = tid + 256 * rr;
        if (idx < 320) {
            const int bi = idx / 10;
            const int o  = idx - bi * 10;
            const float p = x[(size_t)(b0 + bi) * NSITES + LABEL];
            const float q = 1.0f - p;
            float acc = 0.0f;
            #pragma unroll
            for (int d = 0; d < 8; ++d) {
                #pragma unroll
                for (int e = 0; e < 8; ++e) {
                    const float m = fmaf(p, wlsh[(16 * d + 8 + e) * 10 + o],
                                         q * wlsh[(16 * d + e) * 10 + o]);
                    acc = fmaf(vls[bi][d] * rvs[bi][e], m, acc);
                }
            }
            out[(size_t)(b0 + bi) * ODIM + o] = acc;
        }
    }
#undef STEP_L
#undef STEP_R
}

extern "C" void kernel_launch(void* const* d_in, const int* in_sizes, int n_in,
                              void* d_out, int out_size, void* d_ws, size_t ws_size,
                              hipStream_t stream) {
    const float* x     = (const float*)d_in[0];
    const float* w0    = (const float*)d_in[1];
    const float* Wl    = (const float*)d_in[2];
    const float* wlab  = (const float*)d_in[3];
    const float* Wr    = (const float*)d_in[4];
    const float* wlast = (const float*)d_in[5];
    float* out = (float*)d_out;

    mps_fused<<<512, 256, 0, stream>>>(x, w0, Wl, wlab, Wr, wlast, out);
}